// Round 13
// baseline (128.075 us; speedup 1.0000x reference)
//
#include <hip/hip_runtime.h>
#include <hip/hip_bf16.h>

#define T_TASKS 16
#define S_SUP   2048
#define Q_QRY   2048
#define D_IN    256
#define H_HID   512
#define D_EMB   128
#define N_WAY   64
#define NCHUNK  16
#define CHUNK   128   // S_SUP / NCHUNK
#define QB      64    // queries per block in query_mfma
#define BM8     32    // rows per block in embed_mfma8

typedef unsigned short ushortT;
typedef unsigned int uintT;
using bf16x8 = __attribute__((ext_vector_type(8))) short;
using f32x4  = __attribute__((ext_vector_type(4))) float;

__device__ __forceinline__ ushortT f2b(float f) {
    uintT u = __builtin_bit_cast(uintT, f);
    uintT r = u + 0x7FFFu + ((u >> 16) & 1u);   // round-to-nearest-even
    return (ushortT)(r >> 16);
}
__device__ __forceinline__ float b2f(ushortT h) {
    return __builtin_bit_cast(float, (uintT)h << 16);
}
__device__ __forceinline__ uintT pk2(float a, float b) {
    return (uintT)f2b(a) | ((uintT)f2b(b) << 16);
}

// ---------------------------------------------------------------------------
// Convert weights fp32 -> bf16, transposed to [N][K].
// ---------------------------------------------------------------------------
__global__ __launch_bounds__(256) void convert_weights(
    const float* __restrict__ W1, const float* __restrict__ W2,
    ushortT* __restrict__ W1t, ushortT* __restrict__ W2t)
{
    int i = blockIdx.x * 256 + threadIdx.x;
    if (i < D_IN * H_HID) {              // W1 [256][512] -> W1t [512][256]
        int k = i >> 9, n = i & 511;
        W1t[n * D_IN + k] = f2b(W1[i]);
    }
    if (i < H_HID * D_EMB) {             // W2 [512][128] -> W2t [128][512]
        int k = i >> 7, n = i & 127;
        W2t[n * H_HID + k] = f2b(W2[i]);
    }
}

// ---------------------------------------------------------------------------
// embed v8: small blocks for phase de-phasing. 256 thr (4 waves), 32 rows,
// 32 KiB LDS (xs overlays hs) -> 4-5 blocks/CU; 2048 independent blocks.
// Swapped GEMMs (D = W . x^T) with b64-packed epilogues (v7-proven layout).
// G1: wave owns 128-col c-strip x 32 rows; acc[8][2] = 64 regs.
// G2: wave owns 32-col d-strip x 32 rows; acc2[2][2] = 16 regs.
// ---------------------------------------------------------------------------
__global__ __launch_bounds__(256, 4) void embed_mfma8(
    const float* __restrict__ xa, const float* __restrict__ xb,
    const ushortT* __restrict__ W1t, const float* __restrict__ b1,
    const ushortT* __restrict__ W2t, const float* __restrict__ b2,
    ushortT* __restrict__ outa, ushortT* __restrict__ outb)
{
    __shared__ ushortT hs[BM8 * H_HID];   // 32 KiB; xs overlays first 16 KiB
    ushortT* xs = hs;                     // [32][256] swizzled (dead before hs)

    const int tid  = threadIdx.x;
    const int wid  = tid >> 6;
    const int lane = tid & 63;
    const int lr   = lane & 15;
    const int g    = lane >> 4;
    const int bid  = blockIdx.x;
    const float*  x   = (bid < 1024) ? xa : xb;
    ushortT*      out = (bid < 1024) ? outa : outb;
    const long rowbase = (long)(bid & 1023) * BM8;

    // ---- stage x tile (32x256) as bf16 swizzled -------------------------
    #pragma unroll
    for (int i = 0; i < 4; ++i) {
        int ci   = tid + 256 * i;        // 1024 chunks of 8 elems
        int row  = ci >> 5;              // 32 chunks per row
        int col8 = (ci & 31) << 3;
        const float4* p = (const float4*)(x + (rowbase + row) * D_IN + col8);
        float4 a = p[0], b = p[1];
        uint4 v;
        v.x = pk2(a.x, a.y);
        v.y = pk2(a.z, a.w);
        v.z = pk2(b.x, b.y);
        v.w = pk2(b.z, b.w);
        int idx = (row << 8) + col8;
        idx ^= (row & 7) << 3;
        *(uint4*)&xs[idx] = v;
    }
    __syncthreads();

    // ---- G1: D1[c][r] = W1t . x^T, kk-outer, acc[ct][rt] ----------------
    const int c0w = wid * 128;           // wave's 128-col strip
    f32x4 acc[8][2];                     // [c-tile][r-tile] = 64 regs
    #pragma unroll
    for (int ct = 0; ct < 8; ++ct) {
        float4 bv = *(const float4*)&b1[c0w + ct * 16 + g * 4];
        f32x4 a = {bv.x, bv.y, bv.z, bv.w};
        acc[ct][0] = a; acc[ct][1] = a;
    }
    {
        const ushortT* w1p = W1t + (c0w + lr) * D_IN + g * 8;
        #pragma unroll
        for (int kk = 0; kk < 8; ++kk) {
            bf16x8 xf[2];
            #pragma unroll
            for (int rt = 0; rt < 2; ++rt) {
                int rl = rt * 16 + lr;
                int idx = ((rl << 8) + kk * 32 + g * 8) ^ ((rl & 7) << 3);
                xf[rt] = *(const bf16x8*)&xs[idx];
            }
            #pragma unroll
            for (int ct = 0; ct < 8; ++ct) {
                bf16x8 wf = *(const bf16x8*)(w1p + ct * 16 * D_IN + kk * 32);
                acc[ct][0] = __builtin_amdgcn_mfma_f32_16x16x32_bf16(wf, xf[0], acc[ct][0], 0, 0, 0);
                acc[ct][1] = __builtin_amdgcn_mfma_f32_16x16x32_bf16(wf, xf[1], acc[ct][1], 0, 0, 0);
            }
        }
    }
    __syncthreads();   // all xs reads complete -> hs may overwrite

    // ---- G1 epilogue: relu -> b64 swizzled LDS stores -------------------
    #pragma unroll
    for (int ct = 0; ct < 8; ++ct)
        #pragma unroll
        for (int rt = 0; rt < 2; ++rt) {
            uint2 u;
            u.x = pk2(fmaxf(acc[ct][rt][0], 0.f), fmaxf(acc[ct][rt][1], 0.f));
            u.y = pk2(fmaxf(acc[ct][rt][2], 0.f), fmaxf(acc[ct][rt][3], 0.f));
            int r = rt * 16 + lr;
            int c = c0w + ct * 16 + g * 4;
            int idx = (r * H_HID + c) ^ ((r & 7) << 3);
            *(uint2*)&hs[idx] = u;
        }
    __syncthreads();

    // ---- G2: D2[d][r] = W2t . h^T, streamed, b64 global stores ----------
    const int d0 = wid * 32;             // disjoint 32-col strip per wave
    f32x4 acc2[2][2];
    #pragma unroll
    for (int dt = 0; dt < 2; ++dt) {
        float4 bv = *(const float4*)&b2[d0 + dt * 16 + g * 4];
        f32x4 a = {bv.x, bv.y, bv.z, bv.w};
        acc2[dt][0] = a; acc2[dt][1] = a;
    }
    {
        #pragma unroll
        for (int kk = 0; kk < 16; ++kk) {
            bf16x8 bh[2];
            #pragma unroll
            for (int rt = 0; rt < 2; ++rt) {
                int rl = rt * 16 + lr;
                int idx = (rl * H_HID + kk * 32 + g * 8) ^ ((rl & 7) << 3);
                bh[rt] = *(const bf16x8*)&hs[idx];
            }
            #pragma unroll
            for (int dt = 0; dt < 2; ++dt) {
                bf16x8 aw = *(const bf16x8*)(W2t + (d0 + dt * 16 + lr) * H_HID + kk * 32 + g * 8);
                acc2[dt][0] = __builtin_amdgcn_mfma_f32_16x16x32_bf16(aw, bh[0], acc2[dt][0], 0, 0, 0);
                acc2[dt][1] = __builtin_amdgcn_mfma_f32_16x16x32_bf16(aw, bh[1], acc2[dt][1], 0, 0, 0);
            }
        }
    }
    #pragma unroll
    for (int dt = 0; dt < 2; ++dt)
        #pragma unroll
        for (int rt = 0; rt < 2; ++rt) {
            uint2 u;
            u.x = pk2(acc2[dt][rt][0], acc2[dt][rt][1]);
            u.y = pk2(acc2[dt][rt][2], acc2[dt][rt][3]);
            long row = rowbase + rt * 16 + lr;
            *(uint2*)&out[row * D_EMB + d0 + dt * 16 + g * 4] = u;
        }
}

// ---------------------------------------------------------------------------
// Proto phase 1: block = (t, chunk of 128 rows), two LDS accumulation streams.
// ---------------------------------------------------------------------------
__global__ __launch_bounds__(256) void proto_partial(
    const ushortT* __restrict__ se, const int* __restrict__ ids,
    float* __restrict__ psum, int* __restrict__ pcnt)
{
    __shared__ float acc[2][N_WAY][D_EMB];  // 64 KiB
    __shared__ int idbuf[CHUNK];

    const int tid  = threadIdx.x;
    const int t    = blockIdx.x >> 4;
    const int ch   = blockIdx.x & 15;
    const int d    = tid & 127;
    const int half = tid >> 7;

    #pragma unroll
    for (int i = 0; i < 64; ++i)
        ((float*)acc)[tid + 256 * i] = 0.0f;
    if (tid < CHUNK) idbuf[tid] = ids[t * S_SUP + ch * CHUNK + tid];
    __syncthreads();

    const ushortT* sb = se + ((long)t * S_SUP + ch * CHUNK) * D_EMB;
    #pragma unroll 4
    for (int s = 0; s < 64; ++s) {
        int row = half * 64 + s;
        int c = idbuf[row];
        acc[half][c][d] += b2f(sb[(long)row * D_EMB + d]);
    }
    __syncthreads();

    float* pb = psum + (long)blockIdx.x * N_WAY * D_EMB;
    #pragma unroll
    for (int i = 0; i < 32; ++i) {
        int idx = tid + 256 * i;
        pb[idx] = acc[0][idx >> 7][idx & 127] + acc[1][idx >> 7][idx & 127];
    }
    if (tid < N_WAY) {
        int cnt = 0;
        #pragma unroll 8
        for (int s = 0; s < CHUNK; ++s) cnt += (idbuf[s] == tid);
        pcnt[blockIdx.x * N_WAY + tid] = cnt;
    }
}

__global__ __launch_bounds__(256) void proto_reduce(
    const float* __restrict__ psum, const int* __restrict__ pcnt,
    float* __restrict__ protos)
{
    int idx = blockIdx.x * 256 + threadIdx.x;
    int t = idx >> 13;
    int cd = idx & 8191;
    int c = cd >> 7;

    float s = 0.0f;
    int cnt = 0;
    #pragma unroll
    for (int ch = 0; ch < NCHUNK; ++ch) {
        s   += psum[((long)(t * NCHUNK + ch)) * N_WAY * D_EMB + cd];
        cnt += pcnt[(t * NCHUNK + ch) * N_WAY + c];
    }
    protos[idx] = s / (float)(cnt > 0 ? cnt : 1);
}

// ---------------------------------------------------------------------------
// query_mfma: qe bf16 direct fragment loads.
// ---------------------------------------------------------------------------
__global__ __launch_bounds__(256) void query_mfma(
    const ushortT* __restrict__ qe, const float* __restrict__ qy,
    const float* __restrict__ protos_g, float* __restrict__ partials)
{
    __shared__ ushortT psA[N_WAY * D_EMB];       // [c][d] swizzled, 16 KiB
    __shared__ ushortT psT[D_EMB * N_WAY];       // [d][c] swizzled, 16 KiB
    __shared__ ushortT probs_s[4][16 * N_WAY];   // per-wave [q][c] swizzled, 8 KiB
    __shared__ float p2s[N_WAY];
    __shared__ float wloss[4];

    const int tid  = threadIdx.x;
    const int wave = tid >> 6;
    const int lane = tid & 63;
    const int lr   = lane & 15;
    const int lg   = lane >> 4;
    const int t    = blockIdx.x >> 5;        // 32 blocks per task
    const int qblk = blockIdx.x & 31;

    const float* pt = protos_g + (long)t * N_WAY * D_EMB;

    // ---- stage psA [c][d] bf16 swizzled + per-chunk sumsq for p2 --------
    float pp[4];
    #pragma unroll
    for (int i = 0; i < 4; ++i) {
        int ci = tid + 256 * i;
        int c = ci >> 4, col8 = (ci & 15) << 3;
        const float4* p = (const float4*)(pt + c * D_EMB + col8);
        float4 a = p[0], b = p[1];
        ushortT h0 = f2b(a.x), h1 = f2b(a.y), h2 = f2b(a.z), h3 = f2b(a.w);
        ushortT h4 = f2b(b.x), h5 = f2b(b.y), h6 = f2b(b.z), h7 = f2b(b.w);
        float ss = b2f(h0)*b2f(h0) + b2f(h1)*b2f(h1) + b2f(h2)*b2f(h2) + b2f(h3)*b2f(h3)
                 + b2f(h4)*b2f(h4) + b2f(h5)*b2f(h5) + b2f(h6)*b2f(h6) + b2f(h7)*b2f(h7);
        pp[i] = ss;
        uint4 v;
        v.x = (uintT)h0 | ((uintT)h1 << 16);
        v.y = (uintT)h2 | ((uintT)h3 << 16);
        v.z = (uintT)h4 | ((uintT)h5 << 16);
        v.w = (uintT)h6 | ((uintT)h7 << 16);
        int idx = c * D_EMB + col8;
        idx ^= (c & 7) << 3;
        *(uint4*)&psA[idx] = v;
    }
    #pragma unroll
    for (int off = 1; off < 16; off <<= 1) {
        #pragma unroll
        for (int i = 0; i < 4; ++i) pp[i] += __shfl_xor(pp[i], off);
    }
    if ((lane & 15) == 0) {
        int a = wave * 4 + (lane >> 4);
        #pragma unroll
        for (int i = 0; i < 4; ++i) p2s[a + 16 * i] = pp[i];
    }

    // ---- stage psT [d][c] bf16 swizzled ---------------------------------
    {
        int d  = wave * 32 + (lane & 31);
        int ch = lane >> 5;
        #pragma unroll
        for (int m = 0; m < 4; ++m) {
            ushortT hh[8];
            #pragma unroll
            for (int j = 0; j < 8; ++j)
                hh[j] = f2b(pt[(ch * 32 + m * 8 + j) * D_EMB + d]);
            uint4 v;
            v.x = (uintT)hh[0] | ((uintT)hh[1] << 16);
            v.y = (uintT)hh[2] | ((uintT)hh[3] << 16);
            v.z = (uintT)hh[4] | ((uintT)hh[5] << 16);
            v.w = (uintT)hh[6] | ((uintT)hh[7] << 16);
            int idx = d * N_WAY + ch * 32 + m * 8;
            idx ^= (d & 7) << 3;
            *(uint4*)&psT[idx] = v;
        }
    }
    __syncthreads();

    // ---- load qe rows as B-frags (bf16 direct), compute q2 --------------
    const long qrow = (long)t * Q_QRY + qblk * QB + wave * 16 + lr;
    bf16x8 bq[4];
    float q2 = 0.0f;
    #pragma unroll
    for (int kk = 0; kk < 4; ++kk) {
        bq[kk] = *(const bf16x8*)(qe + qrow * D_EMB + kk * 32 + lg * 8);
        #pragma unroll
        for (int j = 0; j < 8; ++j) {
            float v = b2f((ushortT)bq[kk][j]);
            q2 += v * v;
        }
    }
    q2 += __shfl_xor(q2, 16);
    q2 += __shfl_xor(q2, 32);

    // ---- qpT = protos . qe^T --------------------------------------------
    f32x4 acc[4];
    #pragma unroll
    for (int mt = 0; mt < 4; ++mt) { f32x4 z = {0,0,0,0}; acc[mt] = z; }
    #pragma unroll
    for (int kk = 0; kk < 4; ++kk) {
        #pragma unroll
        for (int mt = 0; mt < 4; ++mt) {
            int c = mt * 16 + lr;
            int idx = (c * D_EMB + kk * 32 + lg * 8) ^ ((c & 7) << 3);
            bf16x8 af = *(const bf16x8*)&psA[idx];
            acc[mt] = __builtin_amdgcn_mfma_f32_16x16x32_bf16(af, bq[kk], acc[mt], 0, 0, 0);
        }
    }

    // ---- dist -> in-register softmax over 64 classes --------------------
    float ev[4][4];
    float mx = -1e30f;
    #pragma unroll
    for (int mt = 0; mt < 4; ++mt) {
        #pragma unroll
        for (int r = 0; r < 4; ++r) {
            int c = mt * 16 + lg * 4 + r;
            float d2 = q2 + p2s[c] - 2.0f * acc[mt][r];
            float v = -sqrtf(fmaxf(d2, 0.0f));
            ev[mt][r] = v;
            mx = fmaxf(mx, v);
        }
    }
    mx = fmaxf(mx, __shfl_xor(mx, 16));
    mx = fmaxf(mx, __shfl_xor(mx, 32));
    float sum = 0.0f;
    #pragma unroll
    for (int mt = 0; mt < 4; ++mt)
        #pragma unroll
        for (int r = 0; r < 4; ++r) {
            float e = __expf(ev[mt][r] - mx);
            ev[mt][r] = e;
            sum += e;
        }
    sum += __shfl_xor(sum, 16);
    sum += __shfl_xor(sum, 32);
    float inv = 1.0f / sum;

    // ---- probs -> per-wave LDS tile [q][c] bf16 swizzled ----------------
    #pragma unroll
    for (int mt = 0; mt < 4; ++mt) {
        uintT lo = pk2(ev[mt][0] * inv, ev[mt][1] * inv);
        uintT hi = pk2(ev[mt][2] * inv, ev[mt][3] * inv);
        int idx = lr * N_WAY + ((mt * 16 + lg * 4) ^ ((lr & 7) << 3));
        uint2 v = {lo, hi};
        *(uint2*)&probs_s[wave][idx] = v;
    }

    // ---- pred = probs . protos ------------------------------------------
    f32x4 acc2[8];
    #pragma unroll
    for (int nt = 0; nt < 8; ++nt) { f32x4 z = {0,0,0,0}; acc2[nt] = z; }
    #pragma unroll
    for (int kk = 0; kk < 2; ++kk) {
        int idxa = lr * N_WAY + ((kk * 32 + lg * 8) ^ ((lr & 7) << 3));
        bf16x8 af = *(const bf16x8*)&probs_s[wave][idxa];
        #pragma unroll
        for (int nt = 0; nt < 8; ++nt) {
            int d = nt * 16 + lr;
            int idxb = (d * N_WAY + kk * 32 + lg * 8) ^ ((d & 7) << 3);
            bf16x8 bf = *(const bf16x8*)&psT[idxb];
            acc2[nt] = __builtin_amdgcn_mfma_f32_16x16x32_bf16(af, bf, acc2[nt], 0, 0, 0);
        }
    }

    // ---- fused squared-error loss ---------------------------------------
    float lossacc = 0.0f;
    const long qgbase = (long)t * Q_QRY + qblk * QB + wave * 16;
    #pragma unroll
    for (int r = 0; r < 4; ++r) {
        const float* yrow = qy + (qgbase + lg * 4 + r) * D_EMB;
        #pragma unroll
        for (int nt = 0; nt < 8; ++nt) {
            float diff = acc2[nt][r] - yrow[nt * 16 + lr];
            lossacc += diff * diff;
        }
    }
    #pragma unroll
    for (int off = 32; off >= 1; off >>= 1) lossacc += __shfl_xor(lossacc, off);
    if (lane == 0) wloss[wave] = lossacc;
    __syncthreads();
    if (tid == 0)
        partials[blockIdx.x] = wloss[0] + wloss[1] + wloss[2] + wloss[3];
}

// ---------------------------------------------------------------------------
// Final reduce: 512 partials -> meta_loss scalar
// ---------------------------------------------------------------------------
__global__ __launch_bounds__(256) void reduce_kernel(
    const float* __restrict__ partials, float* __restrict__ out)
{
    __shared__ float wsum[4];
    const int tid = threadIdx.x;
    float s = partials[tid] + partials[tid + 256];
    #pragma unroll
    for (int off = 32; off >= 1; off >>= 1) s += __shfl_xor(s, off);
    if ((tid & 63) == 0) wsum[tid >> 6] = s;
    __syncthreads();
    if (tid == 0) {
        const float inv = 1.0f / ((float)T_TASKS * Q_QRY * D_EMB);
        out[0] = (wsum[0] + wsum[1] + wsum[2] + wsum[3]) * inv;
    }
}

extern "C" void kernel_launch(void* const* d_in, const int* in_sizes, int n_in,
                              void* d_out, int out_size, void* d_ws, size_t ws_size,
                              hipStream_t stream)
{
    const float* support_x = (const float*)d_in[0];
    const int*   support_ids = (const int*)d_in[1];
    const float* query_x  = (const float*)d_in[2];
    const float* query_y  = (const float*)d_in[3];
    const float* W1 = (const float*)d_in[4];
    const float* b1 = (const float*)d_in[5];
    const float* W2 = (const float*)d_in[6];
    const float* b2 = (const float*)d_in[7];

    ushortT* se     = (ushortT*)d_ws;                            // 4.19M bf16
    ushortT* qe     = se + (long)T_TASKS * S_SUP * D_EMB;        // 4.19M bf16
    float* protos   = (float*)(qe + (long)T_TASKS * Q_QRY * D_EMB); // 131072 f
    float* partials = protos + T_TASKS * N_WAY * D_EMB;          // 1024
    ushortT* W1t    = (ushortT*)(partials + 1024);               // 512*256 bf16
    ushortT* W2t    = W1t + H_HID * D_IN;                        // 128*512 bf16
    float* psum     = (float*)(W2t + D_EMB * H_HID);             // 256*64*128 f
    int*   pcnt     = (int*)(psum + (long)T_TASKS * NCHUNK * N_WAY * D_EMB);

    convert_weights<<<512, 256, 0, stream>>>(W1, W2, W1t, W2t);
    embed_mfma8<<<2048, 256, 0, stream>>>(support_x, query_x, W1t, b1, W2t, b2, se, qe);
    proto_partial<<<T_TASKS * NCHUNK, 256, 0, stream>>>(se, support_ids, psum, pcnt);
    proto_reduce<<<512, 256, 0, stream>>>(psum, pcnt, protos);
    query_mfma<<<T_TASKS * (Q_QRY / QB), 256, 0, stream>>>(qe, query_y, protos, partials);
    reduce_kernel<<<1, 256, 0, stream>>>(partials, (float*)d_out);
}